// Round 1
// baseline (13397.467 us; speedup 1.0000x reference)
//
#include <hip/hip_runtime.h>

// Seq2SeqLSTMForecaster on MI355X — all-fp32 VALU, phase-split, register-resident
// recurrent weights.
//
// Phases (all on `stream`, per-chunk interleaved so ys0 scratch stays small):
//   kPrep : transpose the 6 streamed/register [512,128] matrices + W_out1 so
//           loads are lane-coalesced (WT[k*512+j], lanes = consecutive j).
//   kA    : encoder layer 0 recurrence. 256 blocks x 4 batches, 512 threads.
//           thread j owns gate row j of Whh0 (128 VGPRs). h broadcast from LDS
//           (wave-uniform float4 -> free broadcast). Writes ys0[dt][b][hid].
//   kB    : encoder layer 1 recurrence. Whh1 rows in VGPRs; Wih1^T streamed
//           from L2 (256KB/CU/step, coalesced b32) overlapping the dot VALU.
//   kD    : fused decoder (96 steps): L0 (Whh0d in VGPRs) -> L1 (both matrices
//           streamed) -> head (W_out1^T streamed, wave shuffle-reduce) ->
//           scalar pred fed back through LDS.

#define B_    1024
#define T_    672
#define H_    128
#define G_    512      // 4*H
#define TGT_  96
#define CH_   84       // time chunk
#define NCH_  8        // 8 * 84 = 672
#define NBLK_ 256      // blocks; 4 batches per block

__device__ __forceinline__ float sigm(float x)   { return 1.f / (1.f + __expf(-x)); }
__device__ __forceinline__ float tanh_f(float x) { return 1.f - 2.f / (1.f + __expf(2.f * x)); }

// ---------------------------------------------------------------- prep ------
struct PrepArgs {
    const float* s[7];
    float*       d[7];
};

__global__ void kPrep(PrepArgs a) {
    const int m = blockIdx.x;
    if (m < 6) {
        // [512,128] -> [128,512]
        for (int i = threadIdx.x; i < G_ * H_; i += blockDim.x) {
            const int j = i >> 7, k = i & 127;
            a.d[m][k * G_ + j] = a.s[m][i];
        }
    } else {
        // W_out1 [128,128] -> [128,128]^T
        for (int i = threadIdx.x; i < H_ * H_; i += blockDim.x) {
            const int j = i >> 7, k = i & 127;
            a.d[6][k * H_ + j] = a.s[6][i];
        }
    }
}

// ---------------------------------------------------------------- enc L0 ----
__global__ __launch_bounds__(512, 2) void kA(
    const float* __restrict__ feat,   // [B,T]
    const float* __restrict__ whhT,   // [128,512] enc_Whh0^T
    const float* __restrict__ wih0,   // [512] (enc_Wih0 flat)
    const float* __restrict__ bias,   // [512]
    float* __restrict__ ys0,          // [CH_,B,H] chunk buffer
    float* __restrict__ hS, float* __restrict__ cS,  // [B,H] carry
    int t0)
{
    __shared__ __align__(16) float h_sh[H_ * 4];
    __shared__ __align__(16) float z_sh[4 * G_];
    __shared__ __align__(16) float f_sh[CH_ * 4];

    const int tid = threadIdx.x;
    const int B0  = blockIdx.x * 4;

    float w[H_];
#pragma unroll
    for (int k = 0; k < H_; k++) w[k] = whhT[k * G_ + tid];
    const float wx = wih0[tid];
    const float bj = bias[tid];

    for (int i = tid; i < CH_ * 4; i += 512) {
        const int dt = i >> 2, b = i & 3;
        f_sh[i] = feat[(B0 + b) * T_ + t0 + dt];
    }

    const int hid = tid & (H_ - 1), bb = tid >> 7;
    float c;
    if (t0 == 0) {
        c = 0.f;
        h_sh[hid * 4 + bb] = 0.f;
    } else {
        c = cS[(B0 + bb) * H_ + hid];
        h_sh[hid * 4 + bb] = hS[(B0 + bb) * H_ + hid];
    }
    __syncthreads();

    for (int dt = 0; dt < CH_; dt++) {
        const float4 xv = *(const float4*)&f_sh[dt * 4];
        float a0 = __fmaf_rn(xv.x, wx, bj);
        float a1 = __fmaf_rn(xv.y, wx, bj);
        float a2 = __fmaf_rn(xv.z, wx, bj);
        float a3 = __fmaf_rn(xv.w, wx, bj);
#pragma unroll
        for (int k = 0; k < H_; k++) {
            const float4 h4 = *(const float4*)&h_sh[k * 4];  // wave-uniform broadcast
            a0 = __fmaf_rn(h4.x, w[k], a0);
            a1 = __fmaf_rn(h4.y, w[k], a1);
            a2 = __fmaf_rn(h4.z, w[k], a2);
            a3 = __fmaf_rn(h4.w, w[k], a3);
        }
        z_sh[0 * G_ + tid] = a0; z_sh[1 * G_ + tid] = a1;
        z_sh[2 * G_ + tid] = a2; z_sh[3 * G_ + tid] = a3;
        __syncthreads();

        const float zi = z_sh[bb * G_ + hid];
        const float zf = z_sh[bb * G_ + H_ + hid];
        const float zg = z_sh[bb * G_ + 2 * H_ + hid];
        const float zo = z_sh[bb * G_ + 3 * H_ + hid];
        c = sigm(zf) * c + sigm(zi) * tanh_f(zg);
        const float h = sigm(zo) * tanh_f(c);
        h_sh[hid * 4 + bb] = h;
        ys0[dt * (B_ * H_) + (B0 + bb) * H_ + hid] = h;
        __syncthreads();
    }
    hS[(B0 + bb) * H_ + hid] = h_sh[hid * 4 + bb];
    cS[(B0 + bb) * H_ + hid] = c;
}

// ---------------------------------------------------------------- enc L1 ----
__global__ __launch_bounds__(512, 2) void kB(
    const float* __restrict__ ys0,    // [CH_,B,H]
    const float* __restrict__ whhT,   // [128,512] enc_Whh1^T (register-resident)
    const float* __restrict__ wihT,   // [128,512] enc_Wih1^T (streamed)
    const float* __restrict__ bias,   // [512]
    float* __restrict__ hS, float* __restrict__ cS,
    int t0)
{
    __shared__ __align__(16) float h_sh[H_ * 4];
    __shared__ __align__(16) float x_sh[H_ * 4];
    __shared__ __align__(16) float z_sh[4 * G_];

    const int tid = threadIdx.x;
    const int B0  = blockIdx.x * 4;

    float w[H_];
#pragma unroll
    for (int k = 0; k < H_; k++) w[k] = whhT[k * G_ + tid];
    const float bj = bias[tid];

    const int hid = tid & (H_ - 1), bb = tid >> 7;
    float c;
    if (t0 == 0) {
        c = 0.f;
        h_sh[hid * 4 + bb] = 0.f;
    } else {
        c = cS[(B0 + bb) * H_ + hid];
        h_sh[hid * 4 + bb] = hS[(B0 + bb) * H_ + hid];
    }
    x_sh[hid * 4 + bb] = ys0[(B0 + bb) * H_ + hid];  // dt = 0 input
    __syncthreads();

    for (int dt = 0; dt < CH_; dt++) {
        // prefetch next x early so the load overlaps the dot
        float xn = 0.f;
        if (dt + 1 < CH_) xn = ys0[(dt + 1) * (B_ * H_) + (B0 + bb) * H_ + hid];

        float a0 = bj, a1 = bj, a2 = bj, a3 = bj;
#pragma unroll
        for (int k = 0; k < H_; k++) {
            const float4 h4 = *(const float4*)&h_sh[k * 4];
            a0 = __fmaf_rn(h4.x, w[k], a0);
            a1 = __fmaf_rn(h4.y, w[k], a1);
            a2 = __fmaf_rn(h4.z, w[k], a2);
            a3 = __fmaf_rn(h4.w, w[k], a3);
        }
#pragma unroll 8
        for (int k = 0; k < H_; k++) {
            const float  wv = wihT[k * G_ + tid];   // coalesced L2 stream
            const float4 x4 = *(const float4*)&x_sh[k * 4];
            a0 = __fmaf_rn(x4.x, wv, a0);
            a1 = __fmaf_rn(x4.y, wv, a1);
            a2 = __fmaf_rn(x4.z, wv, a2);
            a3 = __fmaf_rn(x4.w, wv, a3);
        }
        z_sh[0 * G_ + tid] = a0; z_sh[1 * G_ + tid] = a1;
        z_sh[2 * G_ + tid] = a2; z_sh[3 * G_ + tid] = a3;
        __syncthreads();

        const float zi = z_sh[bb * G_ + hid];
        const float zf = z_sh[bb * G_ + H_ + hid];
        const float zg = z_sh[bb * G_ + 2 * H_ + hid];
        const float zo = z_sh[bb * G_ + 3 * H_ + hid];
        c = sigm(zf) * c + sigm(zi) * tanh_f(zg);
        const float h = sigm(zo) * tanh_f(c);
        h_sh[hid * 4 + bb] = h;
        x_sh[hid * 4 + bb] = xn;
        __syncthreads();
    }
    hS[(B0 + bb) * H_ + hid] = h_sh[hid * 4 + bb];
    cS[(B0 + bb) * H_ + hid] = c;
}

// ---------------------------------------------------------------- decoder ---
__global__ __launch_bounds__(512, 2) void kD(
    const float* __restrict__ h1S, const float* __restrict__ c1S,
    const float* __restrict__ h2S, const float* __restrict__ c2S,
    const float* __restrict__ whh0T,  // [128,512] dec_Whh0^T (register-resident)
    const float* __restrict__ wih0,   // [512] dec_Wih0 flat
    const float* __restrict__ b0,
    const float* __restrict__ wih1T,  // [128,512] streamed
    const float* __restrict__ whh1T,  // [128,512] streamed
    const float* __restrict__ b1,
    const float* __restrict__ wo1T,   // [128,128] streamed
    const float* __restrict__ bo1,
    const float* __restrict__ wo2,    // [128]
    const float* __restrict__ bo2,    // [1]
    float* __restrict__ out)          // [B,TGT]
{
    __shared__ __align__(16) float h1_sh[H_ * 4];
    __shared__ __align__(16) float h2_sh[H_ * 4];
    __shared__ __align__(16) float z_sh[4 * G_];
    __shared__ __align__(16) float x_sh[4];
    __shared__ float rp[8];

    const int tid = threadIdx.x;
    const int B0  = blockIdx.x * 4;

    float w0[H_];
#pragma unroll
    for (int k = 0; k < H_; k++) w0[k] = whh0T[k * G_ + tid];
    const float wx0 = wih0[tid];
    const float b0j = b0[tid];
    const float b1j = b1[tid];

    const int hid = tid & (H_ - 1), bb = tid >> 7;
    const float wo2v = wo2[hid];
    const float bo1j = bo1[hid];
    const float bo2v = bo2[0];

    float c1 = c1S[(B0 + bb) * H_ + hid];
    float c2 = c2S[(B0 + bb) * H_ + hid];
    h1_sh[hid * 4 + bb] = h1S[(B0 + bb) * H_ + hid];
    h2_sh[hid * 4 + bb] = h2S[(B0 + bb) * H_ + hid];
    if (tid < 4) x_sh[tid] = 0.f;
    __syncthreads();

    for (int s = 0; s < TGT_; s++) {
        // ---- L0 dot (Whh0d in registers) ----
        const float4 xv = *(const float4*)x_sh;
        float a0 = __fmaf_rn(xv.x, wx0, b0j);
        float a1 = __fmaf_rn(xv.y, wx0, b0j);
        float a2 = __fmaf_rn(xv.z, wx0, b0j);
        float a3 = __fmaf_rn(xv.w, wx0, b0j);
#pragma unroll
        for (int k = 0; k < H_; k++) {
            const float4 h4 = *(const float4*)&h1_sh[k * 4];
            a0 = __fmaf_rn(h4.x, w0[k], a0);
            a1 = __fmaf_rn(h4.y, w0[k], a1);
            a2 = __fmaf_rn(h4.z, w0[k], a2);
            a3 = __fmaf_rn(h4.w, w0[k], a3);
        }
        z_sh[0 * G_ + tid] = a0; z_sh[1 * G_ + tid] = a1;
        z_sh[2 * G_ + tid] = a2; z_sh[3 * G_ + tid] = a3;
        __syncthreads();

        // ---- L0 act ----
        {
            const float zi = z_sh[bb * G_ + hid];
            const float zf = z_sh[bb * G_ + H_ + hid];
            const float zg = z_sh[bb * G_ + 2 * H_ + hid];
            const float zo = z_sh[bb * G_ + 3 * H_ + hid];
            c1 = sigm(zf) * c1 + sigm(zi) * tanh_f(zg);
            const float h1v = sigm(zo) * tanh_f(c1);
            h1_sh[hid * 4 + bb] = h1v;
        }
        __syncthreads();

        // ---- L1 dot (both matrices streamed from L2) ----
        float d0 = b1j, d1 = b1j, d2 = b1j, d3 = b1j;
#pragma unroll 4
        for (int k = 0; k < H_; k++) {
            const float  wa = wih1T[k * G_ + tid];
            const float  wb = whh1T[k * G_ + tid];
            const float4 p4 = *(const float4*)&h1_sh[k * 4];
            const float4 q4 = *(const float4*)&h2_sh[k * 4];
            d0 = __fmaf_rn(p4.x, wa, __fmaf_rn(q4.x, wb, d0));
            d1 = __fmaf_rn(p4.y, wa, __fmaf_rn(q4.y, wb, d1));
            d2 = __fmaf_rn(p4.z, wa, __fmaf_rn(q4.z, wb, d2));
            d3 = __fmaf_rn(p4.w, wa, __fmaf_rn(q4.w, wb, d3));
        }
        z_sh[0 * G_ + tid] = d0; z_sh[1 * G_ + tid] = d1;
        z_sh[2 * G_ + tid] = d2; z_sh[3 * G_ + tid] = d3;
        __syncthreads();

        // ---- L1 act ----
        {
            const float zi = z_sh[bb * G_ + hid];
            const float zf = z_sh[bb * G_ + H_ + hid];
            const float zg = z_sh[bb * G_ + 2 * H_ + hid];
            const float zo = z_sh[bb * G_ + 3 * H_ + hid];
            c2 = sigm(zf) * c2 + sigm(zi) * tanh_f(zg);
            const float h2v = sigm(zo) * tanh_f(c2);
            h2_sh[hid * 4 + bb] = h2v;
        }
        __syncthreads();

        // ---- head: relu(h2 @ Wout1^T + bo1) @ Wout2^T + bo2 ----
        float acc = bo1j;
#pragma unroll 8
        for (int k = 0; k < H_; k++)
            acc = __fmaf_rn(h2_sh[k * 4 + bb], wo1T[k * H_ + hid], acc);
        float p = fmaxf(acc, 0.f) * wo2v;
        p += __shfl_down(p, 32);
        p += __shfl_down(p, 16);
        p += __shfl_down(p, 8);
        p += __shfl_down(p, 4);
        p += __shfl_down(p, 2);
        p += __shfl_down(p, 1);
        if ((tid & 63) == 0) rp[tid >> 6] = p;  // wave w covers (bb, half) = (w>>1, w&1)
        __syncthreads();
        if (tid < 4) {
            const float pr = rp[tid * 2] + rp[tid * 2 + 1] + bo2v;
            out[(B0 + tid) * TGT_ + s] = pr;
            x_sh[tid] = pr;
        }
        __syncthreads();
    }
}

// ---------------------------------------------------------------- launch ----
extern "C" void kernel_launch(void* const* d_in, const int* in_sizes, int n_in,
                              void* d_out, int out_size, void* d_ws, size_t ws_size,
                              hipStream_t stream) {
    const float* feat     = (const float*)d_in[0];
    const float* eWih0    = (const float*)d_in[1];
    const float* eWhh0    = (const float*)d_in[2];
    const float* eB0      = (const float*)d_in[3];
    const float* eWih1    = (const float*)d_in[4];
    const float* eWhh1    = (const float*)d_in[5];
    const float* eB1      = (const float*)d_in[6];
    const float* dWih0    = (const float*)d_in[7];
    const float* dWhh0    = (const float*)d_in[8];
    const float* dB0      = (const float*)d_in[9];
    const float* dWih1    = (const float*)d_in[10];
    const float* dWhh1    = (const float*)d_in[11];
    const float* dB1      = (const float*)d_in[12];
    const float* Wo1      = (const float*)d_in[13];
    const float* bo1      = (const float*)d_in[14];
    const float* Wo2      = (const float*)d_in[15];
    const float* bo2      = (const float*)d_in[16];

    float* ws = (float*)d_ws;
    // workspace layout (floats)
    const size_t SZ_YS0 = (size_t)CH_ * B_ * H_;      // 11,010,048
    const size_t SZ_BH  = (size_t)B_ * H_;            // 131,072
    const size_t SZ_W   = (size_t)G_ * H_;            // 65,536
    float* ys0    = ws;
    float* h1S    = ys0 + SZ_YS0;
    float* c1S    = h1S + SZ_BH;
    float* h2S    = c1S + SZ_BH;
    float* c2S    = h2S + SZ_BH;
    float* wtE0   = c2S + SZ_BH;          // enc_Whh0^T
    float* wtE1x  = wtE0 + SZ_W;          // enc_Wih1^T
    float* wtE1h  = wtE1x + SZ_W;         // enc_Whh1^T
    float* wtD0   = wtE1h + SZ_W;         // dec_Whh0^T
    float* wtD1x  = wtD0 + SZ_W;          // dec_Wih1^T
    float* wtD1h  = wtD1x + SZ_W;         // dec_Whh1^T
    float* wtO1   = wtD1h + SZ_W;         // W_out1^T
    // total ~47.8 MB of d_ws

    PrepArgs pa;
    pa.s[0] = eWhh0; pa.d[0] = wtE0;
    pa.s[1] = eWih1; pa.d[1] = wtE1x;
    pa.s[2] = eWhh1; pa.d[2] = wtE1h;
    pa.s[3] = dWhh0; pa.d[3] = wtD0;
    pa.s[4] = dWih1; pa.d[4] = wtD1x;
    pa.s[5] = dWhh1; pa.d[5] = wtD1h;
    pa.s[6] = Wo1;   pa.d[6] = wtO1;
    kPrep<<<7, 256, 0, stream>>>(pa);

    for (int c = 0; c < NCH_; c++) {
        const int t0 = c * CH_;
        kA<<<NBLK_, 512, 0, stream>>>(feat, wtE0, eWih0, eB0, ys0, h1S, c1S, t0);
        kB<<<NBLK_, 512, 0, stream>>>(ys0, wtE1h, wtE1x, eB1, h2S, c2S, t0);
    }
    kD<<<NBLK_, 512, 0, stream>>>(h1S, c1S, h2S, c2S,
                                  wtD0, dWih0, dB0,
                                  wtD1x, wtD1h, dB1,
                                  wtO1, bo1, Wo2, bo2,
                                  (float*)d_out);
}

// Round 2
// 6280.753 us; speedup vs baseline: 2.1331x; 2.1331x over previous
//
#include <hip/hip_runtime.h>

// Seq2SeqLSTMForecaster on MI355X — round 2.
//  - kA  : enc L0 recurrence, split-k (1024 thr, 64 wts/thread, 16 waves/CU)
//  - kX  : X1 = ys0 @ Wih1^T + b1, parallel tiled fp32 GEMM (hoisted out of
//          the sequential loop — this was 84% of round-1 time as kB's L2 stream)
//  - kB2 : enc L1 recurrence, split-k, X1 prefetched into regs during dot
//  - kD  : fused decoder (unchanged from round 1)
// Chunk length CL chosen at runtime from ws_size (X1 chunk is CL*2MB).

#define B_    1024
#define T_    672
#define H_    128
#define G_    512      // 4*H
#define TGT_  96
#define NBLK_ 256      // recurrence blocks; 4 batches per block

__device__ __forceinline__ float sigm(float x)   { return 1.f / (1.f + __expf(-x)); }
__device__ __forceinline__ float tanh_f(float x) { return 1.f - 2.f / (1.f + __expf(2.f * x)); }

// ---------------------------------------------------------------- prep ------
struct PrepArgs {
    const float* s[7];
    float*       d[7];
};

__global__ void kPrep(PrepArgs a) {
    const int m = blockIdx.x;
    if (m < 6) {
        for (int i = threadIdx.x; i < G_ * H_; i += blockDim.x) {
            const int j = i >> 7, k = i & 127;
            a.d[m][k * G_ + j] = a.s[m][i];          // [512,128] -> [128,512]
        }
    } else {
        for (int i = threadIdx.x; i < H_ * H_; i += blockDim.x) {
            const int j = i >> 7, k = i & 127;
            a.d[6][k * H_ + j] = a.s[6][i];          // W_out1 -> W_out1^T
        }
    }
}

// ------------------------------------------------------- enc L0 (split-k) ---
__global__ __launch_bounds__(1024, 4) void kA(
    const float* __restrict__ feat,   // [B,T]
    const float* __restrict__ whhT,   // [128,512] enc_Whh0^T
    const float* __restrict__ wih0,   // [512]
    const float* __restrict__ bias,   // [512]
    float* __restrict__ ys0,          // [CL,B,H]
    float* __restrict__ hS, float* __restrict__ cS,
    int t0, int CL)
{
    __shared__ __align__(16) float h_sh[H_ * 4];     // h[k][b]
    __shared__ __align__(16) float zp[2 * 4 * G_];   // [kh][b][gate]
    __shared__ __align__(16) float f_sh[84 * 4];

    const int tid = threadIdx.x;
    const int j   = tid & (G_ - 1);                  // gate row
    const int kh  = tid >> 9;                        // k-half
    const int B0  = blockIdx.x * 4;

    float w[64];
#pragma unroll
    for (int k = 0; k < 64; k++) w[k] = whhT[(kh * 64 + k) * G_ + j];
    const float wx = wih0[j];
    const float bj = bias[j];

    for (int i = tid; i < CL * 4; i += 1024)
        f_sh[i] = feat[(B0 + (i & 3)) * T_ + t0 + (i >> 2)];

    float c = 0.f;
    if (tid < 512) {
        const int hid = tid & 127, bb = tid >> 7;
        float hv = 0.f;
        if (t0 != 0) { c = cS[(B0 + bb) * H_ + hid]; hv = hS[(B0 + bb) * H_ + hid]; }
        h_sh[hid * 4 + bb] = hv;
    }
    __syncthreads();

    const float* hb = h_sh + kh * 64 * 4;
    for (int dt = 0; dt < CL; dt++) {
        float a0, a1, a2, a3;
        if (kh == 0) {
            const float4 xv = *(const float4*)&f_sh[dt * 4];
            a0 = __fmaf_rn(xv.x, wx, bj);
            a1 = __fmaf_rn(xv.y, wx, bj);
            a2 = __fmaf_rn(xv.z, wx, bj);
            a3 = __fmaf_rn(xv.w, wx, bj);
        } else { a0 = a1 = a2 = a3 = 0.f; }
#pragma unroll
        for (int k = 0; k < 64; k++) {
            const float4 h4 = *(const float4*)&hb[k * 4];   // wave-uniform broadcast
            a0 = __fmaf_rn(h4.x, w[k], a0);
            a1 = __fmaf_rn(h4.y, w[k], a1);
            a2 = __fmaf_rn(h4.z, w[k], a2);
            a3 = __fmaf_rn(h4.w, w[k], a3);
        }
        zp[kh * 2048 + 0 * G_ + j] = a0;
        zp[kh * 2048 + 1 * G_ + j] = a1;
        zp[kh * 2048 + 2 * G_ + j] = a2;
        zp[kh * 2048 + 3 * G_ + j] = a3;
        __syncthreads();

        if (tid < 512) {
            const int hid = tid & 127, bb = tid >> 7;
            const int base = bb * G_ + hid;
            const float zi = zp[base]           + zp[2048 + base];
            const float zf = zp[base + H_]      + zp[2048 + base + H_];
            const float zg = zp[base + 2 * H_]  + zp[2048 + base + 2 * H_];
            const float zo = zp[base + 3 * H_]  + zp[2048 + base + 3 * H_];
            c = sigm(zf) * c + sigm(zi) * tanh_f(zg);
            const float h = sigm(zo) * tanh_f(c);
            h_sh[hid * 4 + bb] = h;
            ys0[(size_t)dt * (B_ * H_) + (B0 + bb) * H_ + hid] = h;
        }
        __syncthreads();
    }
    if (tid < 512) {
        const int hid = tid & 127, bb = tid >> 7;
        hS[(B0 + bb) * H_ + hid] = h_sh[hid * 4 + bb];
        cS[(B0 + bb) * H_ + hid] = c;
    }
}

// ------------------------------------------------- X1 GEMM (fully parallel) -
// X1[m][n] = sum_k ys0[m][k] * wT[k][n] + bias[n],  M = CL*1024, N=512, K=128
#define TM 64
#define TN 64
__global__ __launch_bounds__(256, 2) void kX(
    const float* __restrict__ ys0,    // [M,128]
    const float* __restrict__ wT,     // [128,512]
    const float* __restrict__ bias,   // [512]
    float* __restrict__ X1)           // [M,512]
{
    __shared__ __align__(16) float As[TM][132];   // [m][k], pad 132 (2-way reads: free)
    __shared__ __align__(16) float Bs[128][TN];   // [k][n]

    const int tid = threadIdx.x;
    const int m0 = blockIdx.x * TM;
    const int n0 = blockIdx.y * TN;

    // A tile: 64 rows x 128 k  (coalesced float4, 8 per thread)
    for (int t = tid; t < TM * 32; t += 256) {
        const int r = t >> 5, q = t & 31;
        *(float4*)&As[r][q * 4] = *(const float4*)&ys0[(size_t)(m0 + r) * 128 + q * 4];
    }
    // B tile: 128 k x 64 n
    for (int t = tid; t < 128 * (TN / 4); t += 256) {
        const int k = t >> 4, q = t & 15;
        *(float4*)&Bs[k][q * 4] = *(const float4*)&wT[(size_t)k * G_ + n0 + q * 4];
    }
    __syncthreads();

    const int tx = tid & 15, ty = tid >> 4;
    const int ms = ty * 4, ns = tx * 4;
    float acc[4][4] = {};
#pragma unroll 4
    for (int k = 0; k < 128; k++) {
        const float4 bv = *(const float4*)&Bs[k][ns];
        const float a0 = As[ms + 0][k];
        const float a1 = As[ms + 1][k];
        const float a2 = As[ms + 2][k];
        const float a3 = As[ms + 3][k];
        acc[0][0] = __fmaf_rn(a0, bv.x, acc[0][0]);
        acc[0][1] = __fmaf_rn(a0, bv.y, acc[0][1]);
        acc[0][2] = __fmaf_rn(a0, bv.z, acc[0][2]);
        acc[0][3] = __fmaf_rn(a0, bv.w, acc[0][3]);
        acc[1][0] = __fmaf_rn(a1, bv.x, acc[1][0]);
        acc[1][1] = __fmaf_rn(a1, bv.y, acc[1][1]);
        acc[1][2] = __fmaf_rn(a1, bv.z, acc[1][2]);
        acc[1][3] = __fmaf_rn(a1, bv.w, acc[1][3]);
        acc[2][0] = __fmaf_rn(a2, bv.x, acc[2][0]);
        acc[2][1] = __fmaf_rn(a2, bv.y, acc[2][1]);
        acc[2][2] = __fmaf_rn(a2, bv.z, acc[2][2]);
        acc[2][3] = __fmaf_rn(a2, bv.w, acc[2][3]);
        acc[3][0] = __fmaf_rn(a3, bv.x, acc[3][0]);
        acc[3][1] = __fmaf_rn(a3, bv.y, acc[3][1]);
        acc[3][2] = __fmaf_rn(a3, bv.z, acc[3][2]);
        acc[3][3] = __fmaf_rn(a3, bv.w, acc[3][3]);
    }
    const float4 bv = *(const float4*)&bias[n0 + ns];
#pragma unroll
    for (int i = 0; i < 4; i++) {
        float4 o;
        o.x = acc[i][0] + bv.x;
        o.y = acc[i][1] + bv.y;
        o.z = acc[i][2] + bv.z;
        o.w = acc[i][3] + bv.w;
        *(float4*)&X1[(size_t)(m0 + ms + i) * G_ + n0 + ns] = o;
    }
}

// ----------------------------------------- enc L1 recurrent-only (split-k) --
__global__ __launch_bounds__(1024, 4) void kB2(
    const float* __restrict__ X1,     // [CL,B,512] precomputed x-projection (+bias)
    const float* __restrict__ whhT,   // [128,512] enc_Whh1^T
    float* __restrict__ hS, float* __restrict__ cS,
    int t0, int CL)
{
    __shared__ __align__(16) float h_sh[H_ * 4];
    __shared__ __align__(16) float zp[2 * 4 * G_];

    const int tid = threadIdx.x;
    const int j   = tid & (G_ - 1);
    const int kh  = tid >> 9;
    const int B0  = blockIdx.x * 4;

    float w[64];
#pragma unroll
    for (int k = 0; k < 64; k++) w[k] = whhT[(kh * 64 + k) * G_ + j];

    float c = 0.f;
    if (tid < 512) {
        const int hid = tid & 127, bb = tid >> 7;
        float hv = 0.f;
        if (t0 != 0) { c = cS[(B0 + bb) * H_ + hid]; hv = hS[(B0 + bb) * H_ + hid]; }
        h_sh[hid * 4 + bb] = hv;
    }
    __syncthreads();

    const float* hb = h_sh + kh * 64 * 4;
    for (int dt = 0; dt < CL; dt++) {
        // prefetch this step's x-projection (only the cell-updater threads)
        float xg0 = 0.f, xg1 = 0.f, xg2 = 0.f, xg3 = 0.f;
        if (kh == 0) {
            const size_t xb = ((size_t)dt * B_ + B0 + (j >> 7)) * G_ + (j & 127);
            xg0 = X1[xb];
            xg1 = X1[xb + H_];
            xg2 = X1[xb + 2 * H_];
            xg3 = X1[xb + 3 * H_];
        }
        float a0 = 0.f, a1 = 0.f, a2 = 0.f, a3 = 0.f;
#pragma unroll
        for (int k = 0; k < 64; k++) {
            const float4 h4 = *(const float4*)&hb[k * 4];
            a0 = __fmaf_rn(h4.x, w[k], a0);
            a1 = __fmaf_rn(h4.y, w[k], a1);
            a2 = __fmaf_rn(h4.z, w[k], a2);
            a3 = __fmaf_rn(h4.w, w[k], a3);
        }
        zp[kh * 2048 + 0 * G_ + j] = a0;
        zp[kh * 2048 + 1 * G_ + j] = a1;
        zp[kh * 2048 + 2 * G_ + j] = a2;
        zp[kh * 2048 + 3 * G_ + j] = a3;
        __syncthreads();

        if (tid < 512) {
            const int hid = tid & 127, bb = tid >> 7;
            const int base = bb * G_ + hid;
            const float zi = zp[base]           + zp[2048 + base]           + xg0;
            const float zf = zp[base + H_]      + zp[2048 + base + H_]      + xg1;
            const float zg = zp[base + 2 * H_]  + zp[2048 + base + 2 * H_]  + xg2;
            const float zo = zp[base + 3 * H_]  + zp[2048 + base + 3 * H_]  + xg3;
            c = sigm(zf) * c + sigm(zi) * tanh_f(zg);
            const float h = sigm(zo) * tanh_f(c);
            h_sh[hid * 4 + bb] = h;
        }
        __syncthreads();
    }
    if (tid < 512) {
        const int hid = tid & 127, bb = tid >> 7;
        hS[(B0 + bb) * H_ + hid] = h_sh[hid * 4 + bb];
        cS[(B0 + bb) * H_ + hid] = c;
    }
}

// ---------------------------------------------------------------- decoder ---
__global__ __launch_bounds__(512, 2) void kD(
    const float* __restrict__ h1S, const float* __restrict__ c1S,
    const float* __restrict__ h2S, const float* __restrict__ c2S,
    const float* __restrict__ whh0T,
    const float* __restrict__ wih0,
    const float* __restrict__ b0,
    const float* __restrict__ wih1T,
    const float* __restrict__ whh1T,
    const float* __restrict__ b1,
    const float* __restrict__ wo1T,
    const float* __restrict__ bo1,
    const float* __restrict__ wo2,
    const float* __restrict__ bo2,
    float* __restrict__ out)
{
    __shared__ __align__(16) float h1_sh[H_ * 4];
    __shared__ __align__(16) float h2_sh[H_ * 4];
    __shared__ __align__(16) float z_sh[4 * G_];
    __shared__ __align__(16) float x_sh[4];
    __shared__ float rp[8];

    const int tid = threadIdx.x;
    const int B0  = blockIdx.x * 4;

    float w0[H_];
#pragma unroll
    for (int k = 0; k < H_; k++) w0[k] = whh0T[k * G_ + tid];
    const float wx0 = wih0[tid];
    const float b0j = b0[tid];
    const float b1j = b1[tid];

    const int hid = tid & (H_ - 1), bb = tid >> 7;
    const float wo2v = wo2[hid];
    const float bo1j = bo1[hid];
    const float bo2v = bo2[0];

    float c1 = c1S[(B0 + bb) * H_ + hid];
    float c2 = c2S[(B0 + bb) * H_ + hid];
    h1_sh[hid * 4 + bb] = h1S[(B0 + bb) * H_ + hid];
    h2_sh[hid * 4 + bb] = h2S[(B0 + bb) * H_ + hid];
    if (tid < 4) x_sh[tid] = 0.f;
    __syncthreads();

    for (int s = 0; s < TGT_; s++) {
        const float4 xv = *(const float4*)x_sh;
        float a0 = __fmaf_rn(xv.x, wx0, b0j);
        float a1 = __fmaf_rn(xv.y, wx0, b0j);
        float a2 = __fmaf_rn(xv.z, wx0, b0j);
        float a3 = __fmaf_rn(xv.w, wx0, b0j);
#pragma unroll
        for (int k = 0; k < H_; k++) {
            const float4 h4 = *(const float4*)&h1_sh[k * 4];
            a0 = __fmaf_rn(h4.x, w0[k], a0);
            a1 = __fmaf_rn(h4.y, w0[k], a1);
            a2 = __fmaf_rn(h4.z, w0[k], a2);
            a3 = __fmaf_rn(h4.w, w0[k], a3);
        }
        z_sh[0 * G_ + tid] = a0; z_sh[1 * G_ + tid] = a1;
        z_sh[2 * G_ + tid] = a2; z_sh[3 * G_ + tid] = a3;
        __syncthreads();

        {
            const float zi = z_sh[bb * G_ + hid];
            const float zf = z_sh[bb * G_ + H_ + hid];
            const float zg = z_sh[bb * G_ + 2 * H_ + hid];
            const float zo = z_sh[bb * G_ + 3 * H_ + hid];
            c1 = sigm(zf) * c1 + sigm(zi) * tanh_f(zg);
            h1_sh[hid * 4 + bb] = sigm(zo) * tanh_f(c1);
        }
        __syncthreads();

        float d0 = b1j, d1 = b1j, d2 = b1j, d3 = b1j;
#pragma unroll 4
        for (int k = 0; k < H_; k++) {
            const float  wa = wih1T[k * G_ + tid];
            const float  wb = whh1T[k * G_ + tid];
            const float4 p4 = *(const float4*)&h1_sh[k * 4];
            const float4 q4 = *(const float4*)&h2_sh[k * 4];
            d0 = __fmaf_rn(p4.x, wa, __fmaf_rn(q4.x, wb, d0));
            d1 = __fmaf_rn(p4.y, wa, __fmaf_rn(q4.y, wb, d1));
            d2 = __fmaf_rn(p4.z, wa, __fmaf_rn(q4.z, wb, d2));
            d3 = __fmaf_rn(p4.w, wa, __fmaf_rn(q4.w, wb, d3));
        }
        z_sh[0 * G_ + tid] = d0; z_sh[1 * G_ + tid] = d1;
        z_sh[2 * G_ + tid] = d2; z_sh[3 * G_ + tid] = d3;
        __syncthreads();

        {
            const float zi = z_sh[bb * G_ + hid];
            const float zf = z_sh[bb * G_ + H_ + hid];
            const float zg = z_sh[bb * G_ + 2 * H_ + hid];
            const float zo = z_sh[bb * G_ + 3 * H_ + hid];
            c2 = sigm(zf) * c2 + sigm(zi) * tanh_f(zg);
            h2_sh[hid * 4 + bb] = sigm(zo) * tanh_f(c2);
        }
        __syncthreads();

        float acc = bo1j;
#pragma unroll 8
        for (int k = 0; k < H_; k++)
            acc = __fmaf_rn(h2_sh[k * 4 + bb], wo1T[k * H_ + hid], acc);
        float p = fmaxf(acc, 0.f) * wo2v;
        p += __shfl_down(p, 32);
        p += __shfl_down(p, 16);
        p += __shfl_down(p, 8);
        p += __shfl_down(p, 4);
        p += __shfl_down(p, 2);
        p += __shfl_down(p, 1);
        if ((tid & 63) == 0) rp[tid >> 6] = p;
        __syncthreads();
        if (tid < 4) {
            const float pr = rp[tid * 2] + rp[tid * 2 + 1] + bo2v;
            out[(B0 + tid) * TGT_ + s] = pr;
            x_sh[tid] = pr;
        }
        __syncthreads();
    }
}

// ---------------------------------------------------------------- launch ----
extern "C" void kernel_launch(void* const* d_in, const int* in_sizes, int n_in,
                              void* d_out, int out_size, void* d_ws, size_t ws_size,
                              hipStream_t stream) {
    const float* feat  = (const float*)d_in[0];
    const float* eWih0 = (const float*)d_in[1];
    const float* eWhh0 = (const float*)d_in[2];
    const float* eB0   = (const float*)d_in[3];
    const float* eWih1 = (const float*)d_in[4];
    const float* eWhh1 = (const float*)d_in[5];
    const float* eB1   = (const float*)d_in[6];
    const float* dWih0 = (const float*)d_in[7];
    const float* dWhh0 = (const float*)d_in[8];
    const float* dB0   = (const float*)d_in[9];
    const float* dWih1 = (const float*)d_in[10];
    const float* dWhh1 = (const float*)d_in[11];
    const float* dB1   = (const float*)d_in[12];
    const float* Wo1   = (const float*)d_in[13];
    const float* bo1   = (const float*)d_in[14];
    const float* Wo2   = (const float*)d_in[15];
    const float* bo2   = (const float*)d_in[16];

    const size_t SZ_BH = (size_t)B_ * H_;     // 131072
    const size_t SZ_W  = (size_t)G_ * H_;     // 65536
    const size_t fixed_f = 4 * SZ_BH + 6 * SZ_W + (size_t)H_ * H_ + 64;

    // pick largest chunk length CL (divisor of 672, <=84) fitting ws_size
    static const int cands[] = {84, 56, 48, 42, 28, 24, 21, 16, 14, 12, 8, 7, 6, 4, 3, 2, 1};
    int CL = 1;
    for (int ci = 0; ci < 17; ci++) {
        const size_t need = (fixed_f + (size_t)cands[ci] * B_ * (H_ + G_)) * 4;
        if (need <= ws_size) { CL = cands[ci]; break; }
    }
    const int NC = T_ / CL;

    float* ws   = (float*)d_ws;
    float* ys0  = ws;                                    // [CL,B,H]
    float* X1   = ys0 + (size_t)CL * B_ * H_;            // [CL,B,G]
    float* h1S  = X1 + (size_t)CL * B_ * G_;
    float* c1S  = h1S + SZ_BH;
    float* h2S  = c1S + SZ_BH;
    float* c2S  = h2S + SZ_BH;
    float* wtE0  = c2S + SZ_BH;
    float* wtE1x = wtE0 + SZ_W;
    float* wtE1h = wtE1x + SZ_W;
    float* wtD0  = wtE1h + SZ_W;
    float* wtD1x = wtD0 + SZ_W;
    float* wtD1h = wtD1x + SZ_W;
    float* wtO1  = wtD1h + SZ_W;

    PrepArgs pa;
    pa.s[0] = eWhh0; pa.d[0] = wtE0;
    pa.s[1] = eWih1; pa.d[1] = wtE1x;
    pa.s[2] = eWhh1; pa.d[2] = wtE1h;
    pa.s[3] = dWhh0; pa.d[3] = wtD0;
    pa.s[4] = dWih1; pa.d[4] = wtD1x;
    pa.s[5] = dWhh1; pa.d[5] = wtD1h;
    pa.s[6] = Wo1;   pa.d[6] = wtO1;
    kPrep<<<7, 256, 0, stream>>>(pa);

    for (int c = 0; c < NC; c++) {
        const int t0 = c * CL;
        kA<<<NBLK_, 1024, 0, stream>>>(feat, wtE0, eWih0, eB0, ys0, h1S, c1S, t0, CL);
        kX<<<dim3(CL * 16, 8), 256, 0, stream>>>(ys0, wtE1x, eB1, X1);
        kB2<<<NBLK_, 1024, 0, stream>>>(X1, wtE1h, h2S, c2S, t0, CL);
    }
    kD<<<NBLK_, 512, 0, stream>>>(h1S, c1S, h2S, c2S,
                                  wtD0, dWih0, dB0,
                                  wtD1x, wtD1h, dB1,
                                  wtO1, bo1, Wo2, bo2,
                                  (float*)d_out);
}

// Round 3
// 6200.354 us; speedup vs baseline: 2.1608x; 1.0130x over previous
//
#include <hip/hip_runtime.h>

// Seq2SeqLSTMForecaster on MI355X — round 3.
//  - kA  : enc L0 recurrence (split-k, 1024 thr). Now also emits ys0T in
//          [dt][k][batch] (k-major) layout via a pipelined store of the
//          previous step's h during the dot phase (no extra barriers).
//  - kX  : X1 = ys0 @ Wih1^T + b1 GEMM, rewritten: k-major A, float4 LDS
//          reads on BOTH operands (round-2 version was LDS-bound at 19%
//          VALUBusy from scalar A reads), 8x4 micro-tile, 2-stage K,
//          51 KB LDS -> 3 blocks/CU.
//  - kB2 : enc L1 recurrence (unchanged).
//  - kD  : decoder, rewritten: 1024-thr split-k (16 waves/CU), L1 weights
//          pre-interleaved [k][j][2] (one float2/thread/k), W_out1^T staged
//          in LDS once (saves 64 KB/step L2 restream).

#define B_    1024
#define T_    672
#define H_    128
#define G_    512      // 4*H
#define TGT_  96
#define NBLK_ 256

__device__ __forceinline__ float sigm(float x)   { return 1.f / (1.f + __expf(-x)); }
__device__ __forceinline__ float tanh_f(float x) { return 1.f - 2.f / (1.f + __expf(2.f * x)); }

// ---------------------------------------------------------------- prep ------
struct PrepArgs {
    const float* t_src[4];   // [512,128] -> [128,512] transposes
    float*       t_dst[4];
    const float* wo1;  float* wo1T;    // [128,128] transpose
    const float* d1x;  const float* d1h;  float* pack;  // dec L1 interleave
};

__global__ void kPrep(PrepArgs a) {
    const int m = blockIdx.x;
    if (m < 4) {
        for (int i = threadIdx.x; i < G_ * H_; i += blockDim.x) {
            const int j = i >> 7, k = i & 127;
            a.t_dst[m][k * G_ + j] = a.t_src[m][i];
        }
    } else if (m == 4) {
        for (int i = threadIdx.x; i < H_ * H_; i += blockDim.x) {
            const int j = i >> 7, k = i & 127;
            a.wo1T[k * H_ + j] = a.wo1[i];
        }
    } else {
        // pack[(k*512 + j)*2 + {0,1}] = {dWih1[j][k], dWhh1[j][k]}
        for (int i = threadIdx.x; i < G_ * H_; i += blockDim.x) {
            const int j = i & 511, k = i >> 9;
            a.pack[(k * G_ + j) * 2 + 0] = a.d1x[j * H_ + k];
            a.pack[(k * G_ + j) * 2 + 1] = a.d1h[j * H_ + k];
        }
    }
}

// ------------------------------------------------------- enc L0 (split-k) ---
__global__ __launch_bounds__(1024, 4) void kA(
    const float* __restrict__ feat,   // [B,T]
    const float* __restrict__ whhT,   // [128,512] enc_Whh0^T
    const float* __restrict__ wih0,   // [512]
    const float* __restrict__ bias,   // [512]
    float* __restrict__ ys0T,         // [CL][128][1024]  (k-major!)
    float* __restrict__ hS, float* __restrict__ cS,
    int t0, int CL)
{
    __shared__ __align__(16) float h_sh[H_ * 4];     // [hid][bb]
    __shared__ __align__(16) float zp[2 * 4 * G_];
    __shared__ __align__(16) float f_sh[84 * 4];

    const int tid = threadIdx.x;
    const int j   = tid & (G_ - 1);
    const int kh  = tid >> 9;
    const int B0  = blockIdx.x * 4;

    float w[64];
#pragma unroll
    for (int k = 0; k < 64; k++) w[k] = whhT[(kh * 64 + k) * G_ + j];
    const float wx = wih0[j];
    const float bj = bias[j];

    for (int i = tid; i < CL * 4; i += 1024)
        f_sh[i] = feat[(B0 + (i & 3)) * T_ + t0 + (i >> 2)];

    float c = 0.f;
    if (tid < 512) {
        const int hid = tid & 127, bb = tid >> 7;
        float hv = 0.f;
        if (t0 != 0) { c = cS[(B0 + bb) * H_ + hid]; hv = hS[(B0 + bb) * H_ + hid]; }
        h_sh[hid * 4 + bb] = hv;
    }
    __syncthreads();

    const float* hb = h_sh + kh * 64 * 4;
    for (int dt = 0; dt < CL; dt++) {
        // pipelined store of previous step's h (k-major, coalesced 16B chunks);
        // reads h_sh which stays valid until the act phase of THIS step.
        if (tid < 512 && dt > 0)
            ys0T[((size_t)(dt - 1) * H_ + (tid >> 2)) * B_ + B0 + (tid & 3)] = h_sh[tid];

        float a0, a1, a2, a3;
        if (kh == 0) {
            const float4 xv = *(const float4*)&f_sh[dt * 4];
            a0 = __fmaf_rn(xv.x, wx, bj);
            a1 = __fmaf_rn(xv.y, wx, bj);
            a2 = __fmaf_rn(xv.z, wx, bj);
            a3 = __fmaf_rn(xv.w, wx, bj);
        } else { a0 = a1 = a2 = a3 = 0.f; }
#pragma unroll
        for (int k = 0; k < 64; k++) {
            const float4 h4 = *(const float4*)&hb[k * 4];   // wave-uniform broadcast
            a0 = __fmaf_rn(h4.x, w[k], a0);
            a1 = __fmaf_rn(h4.y, w[k], a1);
            a2 = __fmaf_rn(h4.z, w[k], a2);
            a3 = __fmaf_rn(h4.w, w[k], a3);
        }
        zp[kh * 2048 + 0 * G_ + j] = a0;
        zp[kh * 2048 + 1 * G_ + j] = a1;
        zp[kh * 2048 + 2 * G_ + j] = a2;
        zp[kh * 2048 + 3 * G_ + j] = a3;
        __syncthreads();

        if (tid < 512) {
            const int hid = tid & 127, bb = tid >> 7;
            const int base = bb * G_ + hid;
            const float zi = zp[base]           + zp[2048 + base];
            const float zf = zp[base + H_]      + zp[2048 + base + H_];
            const float zg = zp[base + 2 * H_]  + zp[2048 + base + 2 * H_];
            const float zo = zp[base + 3 * H_]  + zp[2048 + base + 3 * H_];
            c = sigm(zf) * c + sigm(zi) * tanh_f(zg);
            h_sh[hid * 4 + bb] = sigm(zo) * tanh_f(c);
        }
        __syncthreads();
    }
    if (tid < 512) {
        ys0T[((size_t)(CL - 1) * H_ + (tid >> 2)) * B_ + B0 + (tid & 3)] = h_sh[tid];
        const int hid = tid & 127, bb = tid >> 7;
        hS[(B0 + bb) * H_ + hid] = h_sh[hid * 4 + bb];
        cS[(B0 + bb) * H_ + hid] = c;
    }
}

// ------------------------------------------------- X1 GEMM (fully parallel) -
// X1[dt][m][n] = sum_k ys0T[dt][k][m] * wT[k][n] + bias[n]; m=batch (1024)
__global__ __launch_bounds__(256, 3) void kX(
    const float* __restrict__ ys0T,   // [CL][128][1024]
    const float* __restrict__ wT,     // [128][512]
    const float* __restrict__ bias,   // [512]
    float* __restrict__ X1)           // [CL][1024][512]
{
    __shared__ __align__(16) float As[64][132];   // [k][m] tile (33.8 KB)
    __shared__ __align__(16) float Bs[64][68];    // [k][n] tile (17.4 KB)

    const int tid = threadIdx.x;
    const int m0 = blockIdx.x * 128;
    const int n0 = blockIdx.y * 64;
    const int dt = blockIdx.z;
    const float* A = ys0T + (size_t)dt * H_ * B_;

    const int tx = tid & 15, ty = tid >> 4;       // n-quad, m-oct
    float acc[8][4] = {};

#pragma unroll
    for (int ks = 0; ks < 2; ks++) {
        if (ks) __syncthreads();
        // stage A: 64 k-rows x 128 m (straight copy, no transpose needed)
        for (int t = tid; t < 64 * 32; t += 256) {
            const int r = t >> 5, q = t & 31;
            *(float4*)&As[r][q * 4] = *(const float4*)&A[(size_t)(ks * 64 + r) * B_ + m0 + q * 4];
        }
        // stage B: 64 k-rows x 64 n
        for (int t = tid; t < 64 * 16; t += 256) {
            const int r = t >> 4, q = t & 15;
            *(float4*)&Bs[r][q * 4] = *(const float4*)&wT[(size_t)(ks * 64 + r) * G_ + n0 + q * 4];
        }
        __syncthreads();

#pragma unroll 4
        for (int k = 0; k < 64; k++) {
            float av[8];
            *(float4*)&av[0] = *(const float4*)&As[k][ty * 8];
            *(float4*)&av[4] = *(const float4*)&As[k][ty * 8 + 4];
            const float4 bv = *(const float4*)&Bs[k][tx * 4];
#pragma unroll
            for (int i = 0; i < 8; i++) {
                acc[i][0] = __fmaf_rn(av[i], bv.x, acc[i][0]);
                acc[i][1] = __fmaf_rn(av[i], bv.y, acc[i][1]);
                acc[i][2] = __fmaf_rn(av[i], bv.z, acc[i][2]);
                acc[i][3] = __fmaf_rn(av[i], bv.w, acc[i][3]);
            }
        }
    }

    const float4 bvb = *(const float4*)&bias[n0 + tx * 4];
#pragma unroll
    for (int i = 0; i < 8; i++) {
        float4 o;
        o.x = acc[i][0] + bvb.x;
        o.y = acc[i][1] + bvb.y;
        o.z = acc[i][2] + bvb.z;
        o.w = acc[i][3] + bvb.w;
        *(float4*)&X1[((size_t)dt * B_ + m0 + ty * 8 + i) * G_ + n0 + tx * 4] = o;
    }
}

// ----------------------------------------- enc L1 recurrent-only (split-k) --
__global__ __launch_bounds__(1024, 4) void kB2(
    const float* __restrict__ X1,     // [CL][B][512] x-projection (+bias)
    const float* __restrict__ whhT,   // [128,512] enc_Whh1^T
    float* __restrict__ hS, float* __restrict__ cS,
    int t0, int CL)
{
    __shared__ __align__(16) float h_sh[H_ * 4];
    __shared__ __align__(16) float zp[2 * 4 * G_];

    const int tid = threadIdx.x;
    const int j   = tid & (G_ - 1);
    const int kh  = tid >> 9;
    const int B0  = blockIdx.x * 4;

    float w[64];
#pragma unroll
    for (int k = 0; k < 64; k++) w[k] = whhT[(kh * 64 + k) * G_ + j];

    float c = 0.f;
    if (tid < 512) {
        const int hid = tid & 127, bb = tid >> 7;
        float hv = 0.f;
        if (t0 != 0) { c = cS[(B0 + bb) * H_ + hid]; hv = hS[(B0 + bb) * H_ + hid]; }
        h_sh[hid * 4 + bb] = hv;
    }
    __syncthreads();

    const float* hb = h_sh + kh * 64 * 4;
    for (int dt = 0; dt < CL; dt++) {
        float xg0 = 0.f, xg1 = 0.f, xg2 = 0.f, xg3 = 0.f;
        if (kh == 0) {
            const size_t xb = ((size_t)dt * B_ + B0 + (j >> 7)) * G_ + (j & 127);
            xg0 = X1[xb];
            xg1 = X1[xb + H_];
            xg2 = X1[xb + 2 * H_];
            xg3 = X1[xb + 3 * H_];
        }
        float a0 = 0.f, a1 = 0.f, a2 = 0.f, a3 = 0.f;
#pragma unroll
        for (int k = 0; k < 64; k++) {
            const float4 h4 = *(const float4*)&hb[k * 4];
            a0 = __fmaf_rn(h4.x, w[k], a0);
            a1 = __fmaf_rn(h4.y, w[k], a1);
            a2 = __fmaf_rn(h4.z, w[k], a2);
            a3 = __fmaf_rn(h4.w, w[k], a3);
        }
        zp[kh * 2048 + 0 * G_ + j] = a0;
        zp[kh * 2048 + 1 * G_ + j] = a1;
        zp[kh * 2048 + 2 * G_ + j] = a2;
        zp[kh * 2048 + 3 * G_ + j] = a3;
        __syncthreads();

        if (tid < 512) {
            const int hid = tid & 127, bb = tid >> 7;
            const int base = bb * G_ + hid;
            const float zi = zp[base]           + zp[2048 + base]           + xg0;
            const float zf = zp[base + H_]      + zp[2048 + base + H_]      + xg1;
            const float zg = zp[base + 2 * H_]  + zp[2048 + base + 2 * H_]  + xg2;
            const float zo = zp[base + 3 * H_]  + zp[2048 + base + 3 * H_]  + xg3;
            c = sigm(zf) * c + sigm(zi) * tanh_f(zg);
            h_sh[hid * 4 + bb] = sigm(zo) * tanh_f(c);
        }
        __syncthreads();
    }
    if (tid < 512) {
        const int hid = tid & 127, bb = tid >> 7;
        hS[(B0 + bb) * H_ + hid] = h_sh[hid * 4 + bb];
        cS[(B0 + bb) * H_ + hid] = c;
    }
}

// --------------------------------------------------- decoder (split-k 1024) -
__global__ __launch_bounds__(1024, 4) void kD(
    const float* __restrict__ h1S, const float* __restrict__ c1S,
    const float* __restrict__ h2S, const float* __restrict__ c2S,
    const float* __restrict__ whh0T,  // [128][512] dec_Whh0^T (register-resident)
    const float* __restrict__ wih0,   // [512]
    const float* __restrict__ b0,
    const float* __restrict__ packD1, // [128][512][2] interleaved {Wih1,Whh1}^T
    const float* __restrict__ b1,
    const float* __restrict__ wo1T,   // [128][128] (staged to LDS)
    const float* __restrict__ bo1,
    const float* __restrict__ wo2,
    const float* __restrict__ bo2,
    float* __restrict__ out)          // [B,TGT]
{
    __shared__ __align__(16) float h1_sh[H_ * 4];
    __shared__ __align__(16) float h2_sh[H_ * 4];
    __shared__ __align__(16) float zp[2 * 4 * G_];
    __shared__ __align__(16) float wo1s[H_ * H_];   // 64 KB
    __shared__ __align__(16) float x_sh[4];
    __shared__ float rp[8];

    const int tid = threadIdx.x;
    const int j   = tid & (G_ - 1);
    const int kh  = tid >> 9;
    const int B0  = blockIdx.x * 4;

    float w0[64];
#pragma unroll
    for (int k = 0; k < 64; k++) w0[k] = whh0T[(kh * 64 + k) * G_ + j];
    const float wx0 = wih0[j];
    const float b0j = b0[j];
    const float b1j = b1[j];

    // stage W_out1^T into LDS once
    for (int t = tid; t < H_ * H_ / 4; t += 1024)
        *(float4*)&wo1s[t * 4] = *(const float4*)&wo1T[t * 4];

    const int hid = tid & 127, bb = (tid >> 7) & 3;
    float c1 = 0.f, c2 = 0.f, wo2v = 0.f, bo1j = 0.f;
    if (tid < 512) {
        c1 = c1S[(B0 + bb) * H_ + hid];
        c2 = c2S[(B0 + bb) * H_ + hid];
        h1_sh[hid * 4 + bb] = h1S[(B0 + bb) * H_ + hid];
        h2_sh[hid * 4 + bb] = h2S[(B0 + bb) * H_ + hid];
        wo2v = wo2[hid];
        bo1j = bo1[hid];
    }
    const float bo2v = bo2[0];
    if (tid < 4) x_sh[tid] = 0.f;
    __syncthreads();

    const float* hb1 = h1_sh + kh * 64 * 4;
    const float* hb2 = h2_sh + kh * 64 * 4;
    const float* pk  = packD1 + (size_t)kh * 64 * 1024 + (size_t)j * 2;

    for (int s = 0; s < TGT_; s++) {
        // ---- L0 dot ----
        float a0, a1, a2, a3;
        if (kh == 0) {
            const float4 xv = *(const float4*)x_sh;
            a0 = __fmaf_rn(xv.x, wx0, b0j);
            a1 = __fmaf_rn(xv.y, wx0, b0j);
            a2 = __fmaf_rn(xv.z, wx0, b0j);
            a3 = __fmaf_rn(xv.w, wx0, b0j);
        } else { a0 = a1 = a2 = a3 = 0.f; }
#pragma unroll
        for (int k = 0; k < 64; k++) {
            const float4 h4 = *(const float4*)&hb1[k * 4];
            a0 = __fmaf_rn(h4.x, w0[k], a0);
            a1 = __fmaf_rn(h4.y, w0[k], a1);
            a2 = __fmaf_rn(h4.z, w0[k], a2);
            a3 = __fmaf_rn(h4.w, w0[k], a3);
        }
        zp[kh * 2048 + 0 * G_ + j] = a0;
        zp[kh * 2048 + 1 * G_ + j] = a1;
        zp[kh * 2048 + 2 * G_ + j] = a2;
        zp[kh * 2048 + 3 * G_ + j] = a3;
        __syncthreads();

        // ---- L0 act ----
        if (tid < 512) {
            const int base = bb * G_ + hid;
            const float zi = zp[base]           + zp[2048 + base];
            const float zf = zp[base + H_]      + zp[2048 + base + H_];
            const float zg = zp[base + 2 * H_]  + zp[2048 + base + 2 * H_];
            const float zo = zp[base + 3 * H_]  + zp[2048 + base + 3 * H_];
            c1 = sigm(zf) * c1 + sigm(zi) * tanh_f(zg);
            h1_sh[hid * 4 + bb] = sigm(zo) * tanh_f(c1);
        }
        __syncthreads();

        // ---- L1 dot (streamed, interleaved float2 per k) ----
        float d0, d1, d2, d3;
        if (kh == 0) { d0 = d1 = d2 = d3 = b1j; } else { d0 = d1 = d2 = d3 = 0.f; }
#pragma unroll 8
        for (int k = 0; k < 64; k++) {
            const float2 wp = *(const float2*)&pk[(size_t)k * 1024];
            const float4 p4 = *(const float4*)&hb1[k * 4];
            const float4 q4 = *(const float4*)&hb2[k * 4];
            d0 = __fmaf_rn(p4.x, wp.x, __fmaf_rn(q4.x, wp.y, d0));
            d1 = __fmaf_rn(p4.y, wp.x, __fmaf_rn(q4.y, wp.y, d1));
            d2 = __fmaf_rn(p4.z, wp.x, __fmaf_rn(q4.z, wp.y, d2));
            d3 = __fmaf_rn(p4.w, wp.x, __fmaf_rn(q4.w, wp.y, d3));
        }
        zp[kh * 2048 + 0 * G_ + j] = d0;
        zp[kh * 2048 + 1 * G_ + j] = d1;
        zp[kh * 2048 + 2 * G_ + j] = d2;
        zp[kh * 2048 + 3 * G_ + j] = d3;
        __syncthreads();

        // ---- L1 act ----
        if (tid < 512) {
            const int base = bb * G_ + hid;
            const float zi = zp[base]           + zp[2048 + base];
            const float zf = zp[base + H_]      + zp[2048 + base + H_];
            const float zg = zp[base + 2 * H_]  + zp[2048 + base + 2 * H_];
            const float zo = zp[base + 3 * H_]  + zp[2048 + base + 3 * H_];
            c2 = sigm(zf) * c2 + sigm(zi) * tanh_f(zg);
            h2_sh[hid * 4 + bb] = sigm(zo) * tanh_f(c2);
        }
        __syncthreads();

        // ---- head ----
        if (tid < 512) {
            float acc = bo1j;
#pragma unroll 8
            for (int k = 0; k < H_; k++)
                acc = __fmaf_rn(h2_sh[k * 4 + bb], wo1s[k * H_ + hid], acc);
            float p = fmaxf(acc, 0.f) * wo2v;
            p += __shfl_down(p, 32);
            p += __shfl_down(p, 16);
            p += __shfl_down(p, 8);
            p += __shfl_down(p, 4);
            p += __shfl_down(p, 2);
            p += __shfl_down(p, 1);
            if ((tid & 63) == 0) rp[tid >> 6] = p;
        }
        __syncthreads();
        if (tid < 4) {
            const float pr = rp[tid * 2] + rp[tid * 2 + 1] + bo2v;
            out[(B0 + tid) * TGT_ + s] = pr;
            x_sh[tid] = pr;
        }
        __syncthreads();
    }
}

// ---------------------------------------------------------------- launch ----
extern "C" void kernel_launch(void* const* d_in, const int* in_sizes, int n_in,
                              void* d_out, int out_size, void* d_ws, size_t ws_size,
                              hipStream_t stream) {
    const float* feat  = (const float*)d_in[0];
    const float* eWih0 = (const float*)d_in[1];
    const float* eWhh0 = (const float*)d_in[2];
    const float* eB0   = (const float*)d_in[3];
    const float* eWih1 = (const float*)d_in[4];
    const float* eWhh1 = (const float*)d_in[5];
    const float* eB1   = (const float*)d_in[6];
    const float* dWih0 = (const float*)d_in[7];
    const float* dWhh0 = (const float*)d_in[8];
    const float* dB0   = (const float*)d_in[9];
    const float* dWih1 = (const float*)d_in[10];
    const float* dWhh1 = (const float*)d_in[11];
    const float* dB1   = (const float*)d_in[12];
    const float* Wo1   = (const float*)d_in[13];
    const float* bo1   = (const float*)d_in[14];
    const float* Wo2   = (const float*)d_in[15];
    const float* bo2   = (const float*)d_in[16];

    const size_t SZ_BH = (size_t)B_ * H_;     // 131072
    const size_t SZ_W  = (size_t)G_ * H_;     // 65536
    const size_t fixed_f = 4 * SZ_BH + 4 * SZ_W + 2 * SZ_W + (size_t)H_ * H_ + 64;

    static const int cands[] = {84, 56, 48, 42, 28, 24, 21, 16, 14, 12, 8, 7, 6, 4, 3, 2, 1};
    int CL = 1;
    for (int ci = 0; ci < 17; ci++) {
        const size_t need = (fixed_f + (size_t)cands[ci] * B_ * (H_ + G_)) * 4;
        if (need <= ws_size) { CL = cands[ci]; break; }
    }
    const int NC = T_ / CL;

    float* ws    = (float*)d_ws;
    float* ys0T  = ws;                                   // [CL][128][1024]
    float* X1    = ys0T + (size_t)CL * B_ * H_;          // [CL][1024][512]
    float* h1S   = X1 + (size_t)CL * B_ * G_;
    float* c1S   = h1S + SZ_BH;
    float* h2S   = c1S + SZ_BH;
    float* c2S   = h2S + SZ_BH;
    float* wtE0  = c2S + SZ_BH;
    float* wtE1x = wtE0 + SZ_W;
    float* wtE1h = wtE1x + SZ_W;
    float* wtD0  = wtE1h + SZ_W;
    float* wtD1p = wtD0 + SZ_W;            // [128][512][2]
    float* wtO1  = wtD1p + 2 * SZ_W;       // [128][128]

    PrepArgs pa;
    pa.t_src[0] = eWhh0; pa.t_dst[0] = wtE0;
    pa.t_src[1] = eWih1; pa.t_dst[1] = wtE1x;
    pa.t_src[2] = eWhh1; pa.t_dst[2] = wtE1h;
    pa.t_src[3] = dWhh0; pa.t_dst[3] = wtD0;
    pa.wo1 = Wo1; pa.wo1T = wtO1;
    pa.d1x = dWih1; pa.d1h = dWhh1; pa.pack = wtD1p;
    kPrep<<<6, 256, 0, stream>>>(pa);

    for (int c = 0; c < NC; c++) {
        const int t0 = c * CL;
        kA<<<NBLK_, 1024, 0, stream>>>(feat, wtE0, eWih0, eB0, ys0T, h1S, c1S, t0, CL);
        kX<<<dim3(8, 8, CL), 256, 0, stream>>>(ys0T, wtE1x, eB1, X1);
        kB2<<<NBLK_, 1024, 0, stream>>>(X1, wtE1h, h2S, c2S, t0, CL);
    }
    kD<<<NBLK_, 1024, 0, stream>>>(h1S, c1S, h2S, c2S,
                                   wtD0, dWih0, dB0,
                                   wtD1p, dB1,
                                   wtO1, bo1, Wo2, bo2,
                                   (float*)d_out);
}